// Round 7
// baseline (208.937 us; speedup 1.0000x reference)
//
#include <hip/hip_runtime.h>
#include <math.h>

#define NB 32
#define NQ 16
#define NP 196
#define OUTW 3840
#define HM_STRIDE (NQ * NP + NQ)   // 3152, members 0..2
#define HM3_STRIDE (NQ * 49 + NQ)  // 800, member 3

// ---------- resize weights (jax.image.resize, triangle kernel, antialias=True) ----------
template<int N>
__device__ __forceinline__ int calc_w(int i, float* w, int& lo) {
  constexpr float inv = (float)N / 14.0f;          // 4, 2, 0.5 — exact
  constexpr float ks  = (inv > 1.0f) ? inv : 1.0f; // kernel_scale = max(inv_scale, 1)
  constexpr float rks = 1.0f / ks;
  float sf = ((float)i + 0.5f) * inv - 0.5f;
  int l = (int)ceilf(sf - ks);
  int h = (int)floorf(sf + ks);
  if (l < 0) l = 0;
  if (h > N - 1) h = N - 1;
  int n = h - l + 1;
  float sum = 0.f;
  for (int k = 0; k < n; ++k) {
    float t = 1.0f - fabsf((float)(l + k) - sf) * rks;
    t = t > 0.f ? t : 0.f;
    w[k] = t; sum += t;
  }
  float r = 1.0f / sum;
  for (int k = 0; k < n; ++k) w[k] *= r;
  lo = l;
  return n;
}

// ---------- fused resize + stats body, double-buffered plane (T14 async-stage) ----------
template<int N, int PPB, int CH_BLK>
__device__ __forceinline__ void rs_body_db(const float* __restrict__ x,
    const float* __restrict__ W, float* __restrict__ xr,
    float* __restrict__ part, int s, int chunk, int cm,
    float* plane, float* tmp, float* wl,
    float* wya, float* wxa, int* lya, int* lxa, int* nya, int* nxa) {
  constexpr int N2 = N * N, NITER = CH_BLK / PPB;
  constexpr int V = PPB * N2 / 4, I1 = PPB * N * 14;
  constexpr int NR = (V + 255) / 256;
  constexpr int BUF = PPB * N2;   // floats per plane buffer
  const int t = threadIdx.x;
  const int c0 = chunk * CH_BLK;

  if (t < 14)                  nya[t] = calc_w<N>(t, &wya[t * 8], lya[t]);
  else if (t >= 64 && t < 78) { int i = t - 64; nxa[i] = calc_w<N>(i, &wxa[i * 8], lxa[i]); }
  for (int i = t; i < NQ * CH_BLK; i += 256) {
    int q = i / CH_BLK, cc = i - q * CH_BLK;
    wl[i] = W[q * cm + c0 + cc];
  }
  { // prologue: load first plane set directly
    const float4* s4 = (const float4*)(x + ((size_t)s * cm + c0) * N2);
    float4* p4 = (float4*)plane;
    for (int i = t; i < V; i += 256) p4[i] = s4[i];
  }
  __syncthreads();

  float s1 = 0.f, s2 = 0.f, y[NQ];
#pragma unroll
  for (int q = 0; q < NQ; ++q) y[q] = 0.f;

  for (int ci = 0; ci < NITER; ++ci) {
    // stage next-iter planes into registers (latency hides under P1+P2)
    float4 stage[NR];
    if (ci + 1 < NITER) {
      const float4* n4 = (const float4*)(x + ((size_t)s * cm + c0 + (ci + 1) * PPB) * N2);
#pragma unroll
      for (int r = 0; r < NR; ++r) { int i = t + r * 256; if (i < V) stage[r] = n4[i]; }
    }
    // P1: horizontal [N][N] -> [N][14] from current buffer
    const float* pc = plane + (ci & 1) * BUF;
    for (int i = t; i < I1; i += 256) {
      int pl = i / (N * 14), rem = i - pl * (N * 14), r = rem / 14, ox = rem - r * 14;
      const float* base = pc + pl * N2 + r * N + lxa[ox];
      const float* w = &wxa[ox * 8];
      int n = nxa[ox];
      float acc = 0.f;
      for (int k = 0; k < n; ++k) acc = fmaf(w[k], base[k], acc);
      tmp[(pl * N + r) * 15 + ox] = acc;
    }
    __syncthreads();
    // P2: vertical + xr write + stats + Y (196 threads)
    if (t < NP) {
      int oy = t / 14, ox = t - oy * 14;
      int ny = nya[oy], ly = lya[oy];
      const float* wy = &wya[oy * 8];
#pragma unroll
      for (int pl = 0; pl < PPB; ++pl) {
        const float* tc = tmp + (pl * N + ly) * 15 + ox;
        float acc = 0.f;
        for (int k = 0; k < ny; ++k) acc = fmaf(wy[k], tc[k * 15], acc);
        xr[((size_t)s * cm + c0 + ci * PPB + pl) * NP + t] = acc;
        s1 += acc; s2 = fmaf(acc, acc, s2);
        const int wcol = ci * PPB + pl;
#pragma unroll
        for (int q = 0; q < NQ; ++q) y[q] = fmaf(wl[q * CH_BLK + wcol], acc, y[q]);
      }
    }
    // write staged registers into the other buffer (vmcnt waits land here)
    if (ci + 1 < NITER) {
      float4* pn4 = (float4*)(plane + ((ci + 1) & 1) * BUF);
#pragma unroll
      for (int r = 0; r < NR; ++r) { int i = t + r * 256; if (i < V) pn4[i] = stage[r]; }
    }
    __syncthreads();
  }
  if (t < NP) {
    float* pb = part + (size_t)(s * 32 + chunk) * 18 * NP + t;
    pb[0] = s1;
    pb[NP] = s2;
#pragma unroll
    for (int q = 0; q < NQ; ++q) pb[(size_t)(2 + q) * NP] = y[q];
  }
}

// ---------- K1a: members 0+1 in one dispatch (same body shape -> same regalloc) ----------
// grid: m0 [0,1024), m1 [1024,2048)
__global__ __launch_bounds__(256) void k_rs01(
    const float* __restrict__ x0, const float* __restrict__ W0,
    float* __restrict__ xr0, float* __restrict__ part0,
    const float* __restrict__ x1, const float* __restrict__ W1,
    float* __restrict__ xr1, float* __restrict__ part1) {
  __shared__ __align__(16) float plane[2 * 3136];   // dbuf, max member 0
  __shared__ float tmp[840];
  __shared__ float wl[NQ * 16];
  __shared__ float wya[14 * 8], wxa[14 * 8];
  __shared__ int lya[14], lxa[14], nya[14], nxa[14];
  int b = blockIdx.x;
  if (b < 1024) {
    rs_body_db<56, 1, 8>(x0, W0, xr0, part0, b >> 5, b & 31, 256,
                         plane, tmp, wl, wya, wxa, lya, lxa, nya, nxa);
  } else {
    b -= 1024;
    rs_body_db<28, 2, 16>(x1, W1, xr1, part1, b >> 5, b & 31, 512,
                          plane, tmp, wl, wya, wxa, lya, lxa, nya, nxa);
  }
}

// ---------- K1b: members 2+3 in one dispatch ----------
// grid: m2 [0,1024), m3 [1024,2048)
__global__ __launch_bounds__(256) void k_rs23(
    const float* __restrict__ x2, const float* __restrict__ W2, float* __restrict__ part2,
    const float* __restrict__ x3, const float* __restrict__ W3, float* __restrict__ part3) {
  __shared__ __align__(16) float xl[64 * 49 + 16];
  __shared__ float wl[NQ * 64];
  __shared__ float w7a[14 * 8];
  __shared__ int l7a[14], n7a[14];
  int b = blockIdx.x;
  const int t = threadIdx.x;
  if (b < 1024) {
    // member 2: identity resize, register-direct
    if (t >= NP) return;
    const int s = b >> 5, chunk = b & 31;
    const int c0 = chunk * 32;
    const float* src = x2 + ((size_t)s * 1024 + c0) * NP + t;
    float s1 = 0.f, s2 = 0.f, y[NQ];
#pragma unroll
    for (int q = 0; q < NQ; ++q) y[q] = 0.f;
    for (int c = 0; c < 32; ++c) {
      float v = src[(size_t)c * NP];
      s1 += v; s2 = fmaf(v, v, s2);
#pragma unroll
      for (int q = 0; q < NQ; ++q) y[q] = fmaf(W2[q * 1024 + c0 + c], v, y[q]);
    }
    float* pb = part2 + (size_t)(s * 32 + chunk) * 18 * NP + t;
    pb[0] = s1;
    pb[NP] = s2;
#pragma unroll
    for (int q = 0; q < NQ; ++q) pb[(size_t)(2 + q) * NP] = y[q];
  } else {
    // member 3: 7->14 upsample (<=2x2 taps), no xr materialization
    b -= 1024;
    const int s = b >> 5, chunk = b & 31;
    const int c0 = chunk * 64;
    if (t < 14) n7a[t] = calc_w<7>(t, &w7a[t * 8], l7a[t]);
    for (int i = t; i < NQ * 64; i += 256) {
      int q = i >> 6, cc = i & 63;
      wl[i] = W3[q * 2048 + c0 + cc];
    }
    const float4* src4 = (const float4*)(x3 + ((size_t)s * 2048 + c0) * 49);
    float4* x4 = (float4*)xl;
    for (int i = t; i < 64 * 49 / 4; i += 256) x4[i] = src4[i];
    __syncthreads();
    if (t < NP) {
      const int oy = t / 14, ox = t - oy * 14;
      const int ly = l7a[oy], lx = l7a[ox];
      const float wy0 = w7a[oy * 8], wy1 = (n7a[oy] > 1) ? w7a[oy * 8 + 1] : 0.f;
      const float wx0 = w7a[ox * 8], wx1 = (n7a[ox] > 1) ? w7a[ox * 8 + 1] : 0.f;
      const int base0 = ly * 7 + lx;
      float s1 = 0.f, s2 = 0.f, y[NQ];
#pragma unroll
      for (int q = 0; q < NQ; ++q) y[q] = 0.f;
      for (int c = 0; c < 64; ++c) {
        const float* bb = &xl[c * 49 + base0];
        float v = wy0 * fmaf(wx1, bb[1], wx0 * bb[0]) + wy1 * fmaf(wx1, bb[8], wx0 * bb[7]);
        s1 += v; s2 = fmaf(v, v, s2);
#pragma unroll
        for (int q = 0; q < NQ; ++q) y[q] = fmaf(wl[q * 64 + c], v, y[q]);
      }
      float* pb = part3 + (size_t)(s * 32 + chunk) * 18 * NP + t;
      pb[0] = s1;
      pb[NP] = s2;
#pragma unroll
      for (int q = 0; q < NQ; ++q) pb[(size_t)(2 + q) * NP] = y[q];
    }
  }
}

// ---------- K2: combine partials, H, G^-1, HM = rsd*(H^T M), e; m3: adjoint HM ----------
struct HeadArgs {
  const float* part[4];
  const float* W[4];
  float* hm[4];
  int cm[4];
};

__global__ __launch_bounds__(256) void k_head(HeadArgs A) {
  const int m = blockIdx.y, s = blockIdx.x, t = threadIdx.x;
  const int cm = A.cm[m];
  const float* W = A.W[m];
  const float* part = A.part[m];
  float* hm = A.hm[m];

  __shared__ float red[256];
  __shared__ float wsum[NQ];
  __shared__ float Hl[NQ * NP];
  __shared__ float HMl[NQ * NP];
  __shared__ float mul[NP], rsdl[NP];
  __shared__ float aug[16 * 33];
  __shared__ float Ml[256];
  __shared__ float el[NQ];
  __shared__ float w7[14 * 8];
  __shared__ int l7[14], n7[14];
  __shared__ float Radj[14 * 7];
  __shared__ float t2[NQ * 7 * 14];

  { int q = t >> 4, l = t & 15;
    float p = 0.f;
    for (int c = l; c < cm; c += 16) p += W[q * cm + c];
    red[t] = p; }
  __syncthreads();
  if (t < NQ) { float v = 0.f; for (int k = 0; k < 16; ++k) v += red[t * 16 + k]; wsum[t] = v; }
  __syncthreads();

  if (t < NP) {
    float s1 = 0.f, s2 = 0.f, y[NQ];
#pragma unroll
    for (int q = 0; q < NQ; ++q) y[q] = 0.f;
    for (int ch = 0; ch < 32; ++ch) {
      const float* pb = part + (size_t)(s * 32 + ch) * 18 * NP + t;
      s1 += pb[0];
      s2 += pb[NP];
#pragma unroll
      for (int q = 0; q < NQ; ++q) y[q] += pb[(size_t)(2 + q) * NP];
    }
    float mu = s1 / (float)cm;
    float var = (s2 - s1 * mu) / (float)(cm - 1);
    float rsd = (var > 0.f) ? (1.0f / sqrtf(var)) : 0.f;
    mul[t] = mu; rsdl[t] = rsd;
#pragma unroll
    for (int q = 0; q < NQ; ++q) {
      float arg = (y[q] - wsum[q] * mu) * rsd;
      Hl[q * NP + t] = 1.0f / (1.0f + expf(-arg));
    }
  }
  __syncthreads();

  { int q1 = t >> 4, q2 = t & 15;
    float g = 0.f;
    for (int p = 0; p < NP; ++p) g = fmaf(Hl[q1 * NP + p], Hl[q2 * NP + p], g);
    aug[q1 * 33 + q2] = g;
    aug[q1 * 33 + 16 + q2] = (q1 == q2) ? 1.0f : 0.f; }
  __syncthreads();

  for (int k = 0; k < 16; ++k) {
    float rpv = 1.0f / aug[k * 33 + k];
    __syncthreads();
    if (t < 32) aug[k * 33 + t] *= rpv;
    __syncthreads();
    int i = t >> 4, j = t & 15;
    float f = aug[i * 33 + k];
    __syncthreads();
    if (i != k) {
      aug[i * 33 + j]      -= f * aug[k * 33 + j];
      aug[i * 33 + 16 + j] -= f * aug[k * 33 + 16 + j];
    }
    __syncthreads();
  }
  { int i = t >> 4, j = t & 15; Ml[t] = aug[i * 33 + 16 + j]; }
  __syncthreads();

  if (t < NP) {
    float r_ = rsdl[t];
#pragma unroll
    for (int j = 0; j < NQ; ++j) {
      float acc = 0.f;
#pragma unroll
      for (int q = 0; q < NQ; ++q) acc = fmaf(Ml[j * 16 + q], Hl[q * NP + t], acc);
      HMl[j * NP + t] = acc * r_;
    }
  }
  __syncthreads();

  { int j = t >> 4, l = t & 15;
    float p = 0.f;
    for (int pp = l; pp < NP; pp += 16) p = fmaf(mul[pp], HMl[j * NP + pp], p);
    red[t] = p; }
  __syncthreads();
  if (t < NQ) { float v = 0.f; for (int k = 0; k < 16; ++k) v += red[t * 16 + k]; el[t] = v; }
  __syncthreads();

  if (m < 3) {
    float* dst = hm + (size_t)s * HM_STRIDE;
    for (int i = t; i < NQ * NP; i += 256) dst[i] = HMl[i];
    if (t < NQ) dst[NQ * NP + t] = el[t];
  } else {
    if (t < 14) n7[t] = calc_w<7>(t, &w7[t * 8], l7[t]);
    __syncthreads();
    if (t < 98) {
      int oy = t / 7, iy = t - oy * 7;
      int k = iy - l7[oy];
      Radj[oy * 7 + iy] = (k >= 0 && k < n7[oy]) ? w7[oy * 8 + k] : 0.f;
    }
    __syncthreads();
    for (int i = t; i < NQ * 7 * 14; i += 256) {   // t2[j][iy][ox]
      int j = i / 98, rem = i - j * 98, iy = rem / 14, ox = rem - iy * 14;
      float acc = 0.f;
#pragma unroll
      for (int oy = 0; oy < 14; ++oy) acc = fmaf(Radj[oy * 7 + iy], HMl[j * NP + oy * 14 + ox], acc);
      t2[i] = acc;
    }
    __syncthreads();
    float* dst = hm + (size_t)s * HM3_STRIDE;
    for (int i = t; i < NQ * 49; i += 256) {       // dst[j][iy][ix]
      int j = i / 49, rem = i - j * 49, iy = rem / 7, ix = rem - iy * 7;
      float acc = 0.f;
#pragma unroll
      for (int ox = 0; ox < 14; ++ox) acc = fmaf(Radj[ox * 7 + ix], t2[j * 98 + iy * 14 + ox], acc);
      dst[i] = acc;
    }
    if (t < NQ) dst[NQ * 49 + t] = el[t];
  }
}

// ---------- K3: b[cc][j] = dot(row, HM[j]) - e[j]; out = var_j(b) ----------
#define CC3 32
struct VarArgs {
  const float* src[4];
  const float* hm[4];
  int cm[4];
  int ooff[4];
};

// grid: m0 [0,256) m1 [256,768) m2 [768,1792) m3 [1792,3840)
__global__ __launch_bounds__(512) void k_var(VarArgs A, float* __restrict__ out) {
  __shared__ __align__(16) float tile[CC3 * NP];
  __shared__ __align__(16) float hml[NQ * NP];
  __shared__ float el[NQ];
  int b = blockIdx.x;
  int m;
  if (b < 256)       { m = 0; }
  else if (b < 768)  { m = 1; b -= 256; }
  else if (b < 1792) { m = 2; b -= 768; }
  else               { m = 3; b -= 1792; }
  const int t = threadIdx.x;
  const int cc = t >> 4, j = t & 15;

  if (m < 3) {
    const int cm = A.cm[m];
    const int nch = cm / CC3;
    const int s = b / nch;
    const int ch = b % nch;
    const float4* src = (const float4*)(A.src[m] + ((size_t)s * cm + ch * CC3) * NP);
    float4* t4 = (float4*)tile;
    for (int i = t; i < CC3 * NP / 4; i += 512) t4[i] = src[i];
    const float4* hsrc = (const float4*)(A.hm[m] + (size_t)s * HM_STRIDE);
    float4* h4 = (float4*)hml;
    for (int i = t; i < NQ * NP / 4; i += 512) h4[i] = hsrc[i];
    if (t < NQ) el[t] = A.hm[m][(size_t)s * HM_STRIDE + NQ * NP + t];
    __syncthreads();

    const float4* tr = (const float4*)(tile + cc * NP);
    const float4* hr = (const float4*)(hml + j * NP);
    float acc = 0.f;
#pragma unroll 7
    for (int p4 = 0; p4 < NP / 4; ++p4) {
      float4 a = tr[p4], b2 = hr[p4];
      acc = fmaf(a.x, b2.x, acc);
      acc = fmaf(a.y, b2.y, acc);
      acc = fmaf(a.z, b2.z, acc);
      acc = fmaf(a.w, b2.w, acc);
    }
    float bv = acc - el[j];
    float s1 = bv;
    s1 += __shfl_xor(s1, 1, 16); s1 += __shfl_xor(s1, 2, 16);
    s1 += __shfl_xor(s1, 4, 16); s1 += __shfl_xor(s1, 8, 16);
    float mean = s1 * (1.0f / 16.0f);
    float d = bv - mean;
    float s2 = d * d;
    s2 += __shfl_xor(s2, 1, 16); s2 += __shfl_xor(s2, 2, 16);
    s2 += __shfl_xor(s2, 4, 16); s2 += __shfl_xor(s2, 8, 16);
    if (j == 0) out[(size_t)s * OUTW + A.ooff[m] + ch * CC3 + cc] = s2 * (1.0f / 15.0f);
  } else {
    const int s = b / 64;
    const int ch = b % 64;
    const float4* src = (const float4*)(A.src[3] + ((size_t)s * 2048 + ch * CC3) * 49);
    float4* t4 = (float4*)tile;
    for (int i = t; i < CC3 * 49 / 4; i += 512) t4[i] = src[i];
    const float4* hsrc = (const float4*)(A.hm[3] + (size_t)s * HM3_STRIDE);
    float4* h4 = (float4*)hml;
    for (int i = t; i < NQ * 49 / 4; i += 512) h4[i] = hsrc[i];
    if (t < NQ) el[t] = A.hm[3][(size_t)s * HM3_STRIDE + NQ * 49 + t];
    __syncthreads();

    const float* tr = tile + cc * 49;
    const float* hr = hml + j * 49;
    float acc = 0.f;
#pragma unroll
    for (int i = 0; i < 49; ++i) acc = fmaf(tr[i], hr[i], acc);
    float bv = acc - el[j];
    float s1 = bv;
    s1 += __shfl_xor(s1, 1, 16); s1 += __shfl_xor(s1, 2, 16);
    s1 += __shfl_xor(s1, 4, 16); s1 += __shfl_xor(s1, 8, 16);
    float mean = s1 * (1.0f / 16.0f);
    float d = bv - mean;
    float s2 = d * d;
    s2 += __shfl_xor(s2, 1, 16); s2 += __shfl_xor(s2, 2, 16);
    s2 += __shfl_xor(s2, 4, 16); s2 += __shfl_xor(s2, 8, 16);
    if (j == 0) out[(size_t)s * OUTW + 1792 + ch * CC3 + cc] = s2 * (1.0f / 15.0f);
  }
}

extern "C" void kernel_launch(void* const* d_in, const int* in_sizes, int n_in,
                              void* d_out, int out_size, void* d_ws, size_t ws_size,
                              hipStream_t stream) {
  const float* x0 = (const float*)d_in[0];
  const float* W0 = (const float*)d_in[1];
  const float* x1 = (const float*)d_in[2];
  const float* W1 = (const float*)d_in[3];
  const float* x2 = (const float*)d_in[4];
  const float* W2 = (const float*)d_in[5];
  const float* x3 = (const float*)d_in[6];
  const float* W3 = (const float*)d_in[7];
  float* out = (float*)d_out;
  float* ws = (float*)d_ws;

  // workspace layout (floats)
  float* xr0 = ws;                                   // 32*256*196
  float* xr1 = xr0 + (size_t)NB * 256 * NP;          // 32*512*196
  float* part0 = xr1 + (size_t)NB * 512 * NP;
  size_t plm = (size_t)NB * 32 * 18 * NP;            // per member
  float* part1 = part0 + plm;
  float* part2 = part1 + plm;
  float* part3 = part2 + plm;
  float* hm0 = part3 + plm;
  float* hm1 = hm0 + (size_t)NB * HM_STRIDE;
  float* hm2 = hm1 + (size_t)NB * HM_STRIDE;
  float* hm3 = hm2 + (size_t)NB * HM_STRIDE;         // 32*800

  // K1: fused resize+stats, two dispatches
  k_rs01<<<2048, 256, 0, stream>>>(x0, W0, xr0, part0, x1, W1, xr1, part1);
  k_rs23<<<2048, 256, 0, stream>>>(x2, W2, part2, x3, W3, part3);

  // K2: head
  HeadArgs A;
  A.part[0] = part0; A.part[1] = part1; A.part[2] = part2; A.part[3] = part3;
  A.W[0] = W0; A.W[1] = W1; A.W[2] = W2; A.W[3] = W3;
  A.hm[0] = hm0; A.hm[1] = hm1; A.hm[2] = hm2; A.hm[3] = hm3;
  A.cm[0] = 256; A.cm[1] = 512; A.cm[2] = 1024; A.cm[3] = 2048;
  k_head<<<dim3(NB, 4), 256, 0, stream>>>(A);

  // K3: var
  VarArgs V;
  V.src[0] = xr0; V.src[1] = xr1; V.src[2] = x2; V.src[3] = x3;
  V.hm[0] = hm0; V.hm[1] = hm1; V.hm[2] = hm2; V.hm[3] = hm3;
  V.cm[0] = 256; V.cm[1] = 512; V.cm[2] = 1024; V.cm[3] = 2048;
  V.ooff[0] = 0; V.ooff[1] = 256; V.ooff[2] = 768; V.ooff[3] = 1792;
  k_var<<<3840, 512, 0, stream>>>(V, out);
  (void)in_sizes; (void)n_in; (void)out_size; (void)ws_size;
}

// Round 8
// 192.220 us; speedup vs baseline: 1.0870x; 1.0870x over previous
//
#include <hip/hip_runtime.h>
#include <math.h>

#define NB 32
#define NQ 16
#define NP 196
#define OUTW 3840
#define HM_STRIDE (NQ * NP + NQ)   // 3152, members 0..2
#define HM3_STRIDE (NQ * 49 + NQ)  // 800, member 3

// ---------- resize weights (jax.image.resize, triangle kernel, antialias=True) ----------
template<int N>
__device__ __forceinline__ int calc_w(int i, float* w, int& lo) {
  constexpr float inv = (float)N / 14.0f;          // 4, 2, 0.5 — exact
  constexpr float ks  = (inv > 1.0f) ? inv : 1.0f; // kernel_scale = max(inv_scale, 1)
  constexpr float rks = 1.0f / ks;
  float sf = ((float)i + 0.5f) * inv - 0.5f;
  int l = (int)ceilf(sf - ks);
  int h = (int)floorf(sf + ks);
  if (l < 0) l = 0;
  if (h > N - 1) h = N - 1;
  int n = h - l + 1;
  float sum = 0.f;
  for (int k = 0; k < n; ++k) {
    float t = 1.0f - fabsf((float)(l + k) - sf) * rks;
    t = t > 0.f ? t : 0.f;
    w[k] = t; sum += t;
  }
  float r = 1.0f / sum;
  for (int k = 0; k < n; ++k) w[k] *= r;
  for (int k = n; k < 8; ++k) w[k] = 0.f;   // zero-pad: enables fixed-trip tap loops
  lo = l;
  return n;
}

// ---------- K1 (m0/m1): row-per-thread P1 direct from global; single barrier; fused P2 ----------
// grid: 1024 = 32 samples x 32 chunks
template<int N, int CH_BLK>
__global__ __launch_bounds__(256) void k_rs_mem(const float* __restrict__ x,
    const float* __restrict__ W, float* __restrict__ xr,
    float* __restrict__ part, int cm) {
  constexpr int TAPS = (N == 56) ? 8 : 4;   // max horizontal taps
  constexpr int NROW = CH_BLK * N;          // rows handled by this block (448)
  constexpr int RV = N / 4;                 // float4 per row (N%4==0)
  __shared__ float tmp[CH_BLK * N * 15];    // horizontal results [pl*N+r][14] (stride 15)
  __shared__ float wxa[14 * 8], wya[14 * 8];
  __shared__ int lya[14], nya[14];
  __shared__ float wl[NQ * CH_BLK];
  const int t = threadIdx.x;
  const int s = blockIdx.x >> 5, chunk = blockIdx.x & 31;
  const int c0 = chunk * CH_BLK;

  if (t < 14)                 { int dum; calc_w<N>(t, &wxa[t * 8], dum); }
  else if (t >= 64 && t < 78) { int i = t - 64; nya[i] = calc_w<N>(i, &wya[i * 8], lya[i]); }
  for (int i = t; i < NQ * CH_BLK; i += 256) {
    int q = i / CH_BLK, cc = i - q * CH_BLK;
    wl[i] = W[q * cm + c0 + cc];
  }
  __syncthreads();

  // P1: each thread owns full rows; 14 independent float4 loads per row (deep MLP);
  // all row[] indices constant-fold after unroll (lx analytic) -> stays in VGPRs.
  for (int i = t; i < NROW; i += 256) {
    const int pl = i / N, r = i - pl * N;
    const float4* rp = (const float4*)(x + ((size_t)(s * cm + c0 + pl) * N + r) * N);
    float row[N];
#pragma unroll
    for (int j = 0; j < RV; ++j) {
      float4 f = rp[j];
      row[4 * j + 0] = f.x; row[4 * j + 1] = f.y;
      row[4 * j + 2] = f.z; row[4 * j + 3] = f.w;
    }
    float* td = &tmp[i * 15];
#pragma unroll
    for (int ox = 0; ox < 14; ++ox) {
      const int lx0 = (N == 56) ? (4 * ox - 2) : (2 * ox - 1);
      const int lx = lx0 < 0 ? 0 : lx0;
      float acc = 0.f;
#pragma unroll
      for (int k = 0; k < TAPS; ++k) {
        if (lx + k < N) acc = fmaf(wxa[ox * 8 + k], row[lx + k], acc);
      }
      td[ox] = acc;
    }
  }
  __syncthreads();

  // P2: vertical taps + xr write + stats + Y (196 threads)
  if (t < NP) {
    const int oy = t / 14, ox = t - oy * 14;
    const int ny = nya[oy], ly = lya[oy];
    const float* wy = &wya[oy * 8];
    float s1 = 0.f, s2 = 0.f, y[NQ];
#pragma unroll
    for (int q = 0; q < NQ; ++q) y[q] = 0.f;
#pragma unroll
    for (int pl = 0; pl < CH_BLK; ++pl) {
      const float* tc = &tmp[(pl * N + ly) * 15 + ox];
      float acc = 0.f;
      for (int k = 0; k < ny; ++k) acc = fmaf(wy[k], tc[k * 15], acc);
      xr[((size_t)s * cm + c0 + pl) * NP + t] = acc;
      s1 += acc; s2 = fmaf(acc, acc, s2);
#pragma unroll
      for (int q = 0; q < NQ; ++q) y[q] = fmaf(wl[q * CH_BLK + pl], acc, y[q]);
    }
    float* pb = part + (size_t)(s * 32 + chunk) * 18 * NP + t;
    pb[0] = s1;
    pb[NP] = s2;
#pragma unroll
    for (int q = 0; q < NQ; ++q) pb[(size_t)(2 + q) * NP] = y[q];
  }
}

// ---------- K1c: member 2 (identity resize), register-direct, coalesced ----------
__global__ __launch_bounds__(256) void k_rs2(const float* __restrict__ x,
    const float* __restrict__ W, float* __restrict__ part) {
  const int t = threadIdx.x;
  if (t >= NP) return;
  const int s = blockIdx.x >> 5, chunk = blockIdx.x & 31;
  const int c0 = chunk * 32;
  const float* src = x + ((size_t)s * 1024 + c0) * NP + t;
  float s1 = 0.f, s2 = 0.f, y[NQ];
#pragma unroll
  for (int q = 0; q < NQ; ++q) y[q] = 0.f;
  for (int c = 0; c < 32; ++c) {
    float v = src[(size_t)c * NP];
    s1 += v; s2 = fmaf(v, v, s2);
#pragma unroll
    for (int q = 0; q < NQ; ++q) y[q] = fmaf(W[q * 1024 + c0 + c], v, y[q]);
  }
  float* pb = part + (size_t)(s * 32 + chunk) * 18 * NP + t;
  pb[0] = s1;
  pb[NP] = s2;
#pragma unroll
  for (int q = 0; q < NQ; ++q) pb[(size_t)(2 + q) * NP] = y[q];
}

// ---------- K1d: member 3 (7->14 upsample, <=2x2 taps, no xr) ----------
__global__ __launch_bounds__(256) void k_rs3(const float* __restrict__ x,
    const float* __restrict__ W, float* __restrict__ part) {
  __shared__ __align__(16) float xl[64 * 49 + 16];
  __shared__ float wl[NQ * 64];
  __shared__ float w7a[14 * 8];
  __shared__ int l7a[14], n7a[14];
  const int t = threadIdx.x;
  const int s = blockIdx.x >> 5, chunk = blockIdx.x & 31;
  const int c0 = chunk * 64;

  if (t < 14) n7a[t] = calc_w<7>(t, &w7a[t * 8], l7a[t]);
  for (int i = t; i < NQ * 64; i += 256) {
    int q = i >> 6, cc = i & 63;
    wl[i] = W[q * 2048 + c0 + cc];
  }
  const float4* src4 = (const float4*)(x + ((size_t)s * 2048 + c0) * 49);
  float4* x4 = (float4*)xl;
  for (int i = t; i < 64 * 49 / 4; i += 256) x4[i] = src4[i];
  __syncthreads();

  if (t < NP) {
    const int oy = t / 14, ox = t - oy * 14;
    const int ly = l7a[oy], lx = l7a[ox];
    const float wy0 = w7a[oy * 8], wy1 = (n7a[oy] > 1) ? w7a[oy * 8 + 1] : 0.f;
    const float wx0 = w7a[ox * 8], wx1 = (n7a[ox] > 1) ? w7a[ox * 8 + 1] : 0.f;
    const int base0 = ly * 7 + lx;
    float s1 = 0.f, s2 = 0.f, y[NQ];
#pragma unroll
    for (int q = 0; q < NQ; ++q) y[q] = 0.f;
    for (int c = 0; c < 64; ++c) {
      const float* bb = &xl[c * 49 + base0];
      float v = wy0 * fmaf(wx1, bb[1], wx0 * bb[0]) + wy1 * fmaf(wx1, bb[8], wx0 * bb[7]);
      s1 += v; s2 = fmaf(v, v, s2);
#pragma unroll
      for (int q = 0; q < NQ; ++q) y[q] = fmaf(wl[q * 64 + c], v, y[q]);
    }
    float* pb = part + (size_t)(s * 32 + chunk) * 18 * NP + t;
    pb[0] = s1;
    pb[NP] = s2;
#pragma unroll
    for (int q = 0; q < NQ; ++q) pb[(size_t)(2 + q) * NP] = y[q];
  }
}

// ---------- K2: combine partials, H, G^-1, HM = rsd*(H^T M), e; m3: adjoint HM ----------
struct HeadArgs {
  const float* part[4];
  const float* W[4];
  float* hm[4];
  int cm[4];
};

__global__ __launch_bounds__(256) void k_head(HeadArgs A) {
  const int m = blockIdx.y, s = blockIdx.x, t = threadIdx.x;
  const int cm = A.cm[m];
  const float* W = A.W[m];
  const float* part = A.part[m];
  float* hm = A.hm[m];

  __shared__ float red[256];
  __shared__ float wsum[NQ];
  __shared__ float Hl[NQ * NP];
  __shared__ float HMl[NQ * NP];
  __shared__ float mul[NP], rsdl[NP];
  __shared__ float aug[16 * 33];
  __shared__ float Ml[256];
  __shared__ float el[NQ];
  __shared__ float w7[14 * 8];
  __shared__ int l7[14], n7[14];
  __shared__ float Radj[14 * 7];
  __shared__ float t2[NQ * 7 * 14];

  { int q = t >> 4, l = t & 15;
    float p = 0.f;
    for (int c = l; c < cm; c += 16) p += W[q * cm + c];
    red[t] = p; }
  __syncthreads();
  if (t < NQ) { float v = 0.f; for (int k = 0; k < 16; ++k) v += red[t * 16 + k]; wsum[t] = v; }
  __syncthreads();

  if (t < NP) {
    float s1 = 0.f, s2 = 0.f, y[NQ];
#pragma unroll
    for (int q = 0; q < NQ; ++q) y[q] = 0.f;
    for (int ch = 0; ch < 32; ++ch) {
      const float* pb = part + (size_t)(s * 32 + ch) * 18 * NP + t;
      s1 += pb[0];
      s2 += pb[NP];
#pragma unroll
      for (int q = 0; q < NQ; ++q) y[q] += pb[(size_t)(2 + q) * NP];
    }
    float mu = s1 / (float)cm;
    float var = (s2 - s1 * mu) / (float)(cm - 1);
    float rsd = (var > 0.f) ? (1.0f / sqrtf(var)) : 0.f;
    mul[t] = mu; rsdl[t] = rsd;
#pragma unroll
    for (int q = 0; q < NQ; ++q) {
      float arg = (y[q] - wsum[q] * mu) * rsd;
      Hl[q * NP + t] = 1.0f / (1.0f + expf(-arg));
    }
  }
  __syncthreads();

  { int q1 = t >> 4, q2 = t & 15;
    float g = 0.f;
    for (int p = 0; p < NP; ++p) g = fmaf(Hl[q1 * NP + p], Hl[q2 * NP + p], g);
    aug[q1 * 33 + q2] = g;
    aug[q1 * 33 + 16 + q2] = (q1 == q2) ? 1.0f : 0.f; }
  __syncthreads();

  for (int k = 0; k < 16; ++k) {
    float rpv = 1.0f / aug[k * 33 + k];
    __syncthreads();
    if (t < 32) aug[k * 33 + t] *= rpv;
    __syncthreads();
    int i = t >> 4, j = t & 15;
    float f = aug[i * 33 + k];
    __syncthreads();
    if (i != k) {
      aug[i * 33 + j]      -= f * aug[k * 33 + j];
      aug[i * 33 + 16 + j] -= f * aug[k * 33 + 16 + j];
    }
    __syncthreads();
  }
  { int i = t >> 4, j = t & 15; Ml[t] = aug[i * 33 + 16 + j]; }
  __syncthreads();

  if (t < NP) {
    float r_ = rsdl[t];
#pragma unroll
    for (int j = 0; j < NQ; ++j) {
      float acc = 0.f;
#pragma unroll
      for (int q = 0; q < NQ; ++q) acc = fmaf(Ml[j * 16 + q], Hl[q * NP + t], acc);
      HMl[j * NP + t] = acc * r_;
    }
  }
  __syncthreads();

  { int j = t >> 4, l = t & 15;
    float p = 0.f;
    for (int pp = l; pp < NP; pp += 16) p = fmaf(mul[pp], HMl[j * NP + pp], p);
    red[t] = p; }
  __syncthreads();
  if (t < NQ) { float v = 0.f; for (int k = 0; k < 16; ++k) v += red[t * 16 + k]; el[t] = v; }
  __syncthreads();

  if (m < 3) {
    float* dst = hm + (size_t)s * HM_STRIDE;
    for (int i = t; i < NQ * NP; i += 256) dst[i] = HMl[i];
    if (t < NQ) dst[NQ * NP + t] = el[t];
  } else {
    if (t < 14) n7[t] = calc_w<7>(t, &w7[t * 8], l7[t]);
    __syncthreads();
    if (t < 98) {
      int oy = t / 7, iy = t - oy * 7;
      int k = iy - l7[oy];
      Radj[oy * 7 + iy] = (k >= 0 && k < n7[oy]) ? w7[oy * 8 + k] : 0.f;
    }
    __syncthreads();
    for (int i = t; i < NQ * 7 * 14; i += 256) {   // t2[j][iy][ox]
      int j = i / 98, rem = i - j * 98, iy = rem / 14, ox = rem - iy * 14;
      float acc = 0.f;
#pragma unroll
      for (int oy = 0; oy < 14; ++oy) acc = fmaf(Radj[oy * 7 + iy], HMl[j * NP + oy * 14 + ox], acc);
      t2[i] = acc;
    }
    __syncthreads();
    float* dst = hm + (size_t)s * HM3_STRIDE;
    for (int i = t; i < NQ * 49; i += 256) {       // dst[j][iy][ix]
      int j = i / 49, rem = i - j * 49, iy = rem / 7, ix = rem - iy * 7;
      float acc = 0.f;
#pragma unroll
      for (int ox = 0; ox < 14; ++ox) acc = fmaf(Radj[ox * 7 + ix], t2[j * 98 + iy * 14 + ox], acc);
      dst[i] = acc;
    }
    if (t < NQ) dst[NQ * 49 + t] = el[t];
  }
}

// ---------- K3: b[cc][j] = dot(row, HM[j]) - e[j]; out = var_j(b) ----------
#define CC3 32
struct VarArgs {
  const float* src[4];
  const float* hm[4];
  int cm[4];
  int ooff[4];
};

// grid: m0 [0,256) m1 [256,768) m2 [768,1792) m3 [1792,3840)
__global__ __launch_bounds__(512) void k_var(VarArgs A, float* __restrict__ out) {
  __shared__ __align__(16) float tile[CC3 * NP];
  __shared__ __align__(16) float hml[NQ * NP];
  __shared__ float el[NQ];
  int b = blockIdx.x;
  int m;
  if (b < 256)       { m = 0; }
  else if (b < 768)  { m = 1; b -= 256; }
  else if (b < 1792) { m = 2; b -= 768; }
  else               { m = 3; b -= 1792; }
  const int t = threadIdx.x;
  const int cc = t >> 4, j = t & 15;

  if (m < 3) {
    const int cm = A.cm[m];
    const int nch = cm / CC3;
    const int s = b / nch;
    const int ch = b % nch;
    const float4* src = (const float4*)(A.src[m] + ((size_t)s * cm + ch * CC3) * NP);
    float4* t4 = (float4*)tile;
    for (int i = t; i < CC3 * NP / 4; i += 512) t4[i] = src[i];
    const float4* hsrc = (const float4*)(A.hm[m] + (size_t)s * HM_STRIDE);
    float4* h4 = (float4*)hml;
    for (int i = t; i < NQ * NP / 4; i += 512) h4[i] = hsrc[i];
    if (t < NQ) el[t] = A.hm[m][(size_t)s * HM_STRIDE + NQ * NP + t];
    __syncthreads();

    const float4* tr = (const float4*)(tile + cc * NP);
    const float4* hr = (const float4*)(hml + j * NP);
    float acc = 0.f;
#pragma unroll 7
    for (int p4 = 0; p4 < NP / 4; ++p4) {
      float4 a = tr[p4], b2 = hr[p4];
      acc = fmaf(a.x, b2.x, acc);
      acc = fmaf(a.y, b2.y, acc);
      acc = fmaf(a.z, b2.z, acc);
      acc = fmaf(a.w, b2.w, acc);
    }
    float bv = acc - el[j];
    float s1 = bv;
    s1 += __shfl_xor(s1, 1, 16); s1 += __shfl_xor(s1, 2, 16);
    s1 += __shfl_xor(s1, 4, 16); s1 += __shfl_xor(s1, 8, 16);
    float mean = s1 * (1.0f / 16.0f);
    float d = bv - mean;
    float s2 = d * d;
    s2 += __shfl_xor(s2, 1, 16); s2 += __shfl_xor(s2, 2, 16);
    s2 += __shfl_xor(s2, 4, 16); s2 += __shfl_xor(s2, 8, 16);
    if (j == 0) out[(size_t)s * OUTW + A.ooff[m] + ch * CC3 + cc] = s2 * (1.0f / 15.0f);
  } else {
    const int s = b / 64;
    const int ch = b % 64;
    const float4* src = (const float4*)(A.src[3] + ((size_t)s * 2048 + ch * CC3) * 49);
    float4* t4 = (float4*)tile;
    for (int i = t; i < CC3 * 49 / 4; i += 512) t4[i] = src[i];
    const float4* hsrc = (const float4*)(A.hm[3] + (size_t)s * HM3_STRIDE);
    float4* h4 = (float4*)hml;
    for (int i = t; i < NQ * 49 / 4; i += 512) h4[i] = hsrc[i];
    if (t < NQ) el[t] = A.hm[3][(size_t)s * HM3_STRIDE + NQ * 49 + t];
    __syncthreads();

    const float* tr = tile + cc * 49;
    const float* hr = hml + j * 49;
    float acc = 0.f;
#pragma unroll
    for (int i = 0; i < 49; ++i) acc = fmaf(tr[i], hr[i], acc);
    float bv = acc - el[j];
    float s1 = bv;
    s1 += __shfl_xor(s1, 1, 16); s1 += __shfl_xor(s1, 2, 16);
    s1 += __shfl_xor(s1, 4, 16); s1 += __shfl_xor(s1, 8, 16);
    float mean = s1 * (1.0f / 16.0f);
    float d = bv - mean;
    float s2 = d * d;
    s2 += __shfl_xor(s2, 1, 16); s2 += __shfl_xor(s2, 2, 16);
    s2 += __shfl_xor(s2, 4, 16); s2 += __shfl_xor(s2, 8, 16);
    if (j == 0) out[(size_t)s * OUTW + 1792 + ch * CC3 + cc] = s2 * (1.0f / 15.0f);
  }
}

extern "C" void kernel_launch(void* const* d_in, const int* in_sizes, int n_in,
                              void* d_out, int out_size, void* d_ws, size_t ws_size,
                              hipStream_t stream) {
  const float* x0 = (const float*)d_in[0];
  const float* W0 = (const float*)d_in[1];
  const float* x1 = (const float*)d_in[2];
  const float* W1 = (const float*)d_in[3];
  const float* x2 = (const float*)d_in[4];
  const float* W2 = (const float*)d_in[5];
  const float* x3 = (const float*)d_in[6];
  const float* W3 = (const float*)d_in[7];
  float* out = (float*)d_out;
  float* ws = (float*)d_ws;

  // workspace layout (floats)
  float* xr0 = ws;                                   // 32*256*196
  float* xr1 = xr0 + (size_t)NB * 256 * NP;          // 32*512*196
  float* part0 = xr1 + (size_t)NB * 512 * NP;
  size_t plm = (size_t)NB * 32 * 18 * NP;            // per member
  float* part1 = part0 + plm;
  float* part2 = part1 + plm;
  float* part3 = part2 + plm;
  float* hm0 = part3 + plm;
  float* hm1 = hm0 + (size_t)NB * HM_STRIDE;
  float* hm2 = hm1 + (size_t)NB * HM_STRIDE;
  float* hm3 = hm2 + (size_t)NB * HM_STRIDE;         // 32*800

  // K1: per-member fused resize+stats (separate kernels -> separate regalloc)
  k_rs_mem<56, 8><<<1024, 256, 0, stream>>>(x0, W0, xr0, part0, 256);
  k_rs_mem<28, 16><<<1024, 256, 0, stream>>>(x1, W1, xr1, part1, 512);
  k_rs2<<<1024, 256, 0, stream>>>(x2, W2, part2);
  k_rs3<<<1024, 256, 0, stream>>>(x3, W3, part3);

  // K2: head
  HeadArgs A;
  A.part[0] = part0; A.part[1] = part1; A.part[2] = part2; A.part[3] = part3;
  A.W[0] = W0; A.W[1] = W1; A.W[2] = W2; A.W[3] = W3;
  A.hm[0] = hm0; A.hm[1] = hm1; A.hm[2] = hm2; A.hm[3] = hm3;
  A.cm[0] = 256; A.cm[1] = 512; A.cm[2] = 1024; A.cm[3] = 2048;
  k_head<<<dim3(NB, 4), 256, 0, stream>>>(A);

  // K3: var
  VarArgs V;
  V.src[0] = xr0; V.src[1] = xr1; V.src[2] = x2; V.src[3] = x3;
  V.hm[0] = hm0; V.hm[1] = hm1; V.hm[2] = hm2; V.hm[3] = hm3;
  V.cm[0] = 256; V.cm[1] = 512; V.cm[2] = 1024; V.cm[3] = 2048;
  V.ooff[0] = 0; V.ooff[1] = 256; V.ooff[2] = 768; V.ooff[3] = 1792;
  k_var<<<3840, 512, 0, stream>>>(V, out);
  (void)in_sizes; (void)n_in; (void)out_size; (void)ws_size;
}